// Round 1
// baseline (437.332 us; speedup 1.0000x reference)
//
#include <hip/hip_runtime.h>
#include <cstdint>

#define N 8192
#define FIN 256
#define FOUT 128
#define ALPHA 0.2f
#define JP 4                  // j-split
#define JSL (N / JP)          // 2048 j per block
#define TJ 64                 // j-tile
#define NTILE (JSL / TJ)      // 32 tiles
#define RB 32                 // rows per block
#define SST 72                // S stride in u16 (16B-aligned rows, baseline banks)

typedef unsigned short u16;
typedef __attribute__((ext_vector_type(8))) short short8;
typedef __attribute__((ext_vector_type(4))) float floatx4;

__device__ __forceinline__ u16 bf16_rne(float f) {
  uint32_t u = __float_as_uint(f);
  u += 0x7fff + ((u >> 16) & 1);
  return (u16)(u >> 16);
}

// async global->LDS DMA, 16 B per lane, whole wave. LDS dest = uniform base
// + lane*16 (m104: wave-uniform base, lane-contiguous — layout must match).
__device__ __forceinline__ void gl_lds16(const void* g, void* l) {
  __builtin_amdgcn_global_load_lds(
      (const __attribute__((address_space(1))) void*)g,
      (__attribute__((address_space(3))) void*)l, 16, 0, 0);
}

// ---------------------------------------------------------------------------
// Kernel 1: h = x@W (fp32); hT3 bf16 tiled [jb][nt][m*4+q][8] (1-KB chunks,
// DMA- and wave-contiguous); src = h@a1, dst = h@a2.  (unchanged)
// ---------------------------------------------------------------------------
__global__ __launch_bounds__(256) void k_proj(const float* __restrict__ x,
                                              const float* __restrict__ W,
                                              const float* __restrict__ a,
                                              u16* __restrict__ hT3,
                                              float* __restrict__ srcv,
                                              float* __restrict__ dstv) {
  __shared__ float xs[8 * FIN];                     // 8 KB
  __shared__ float partS[4][4], partD[4][4];
  const int t = threadIdx.x;
  const int R0 = blockIdx.x * 8;

  const float4* xv = (const float4*)(x + (size_t)R0 * FIN);
  float4* xsv = (float4*)xs;
  xsv[t] = xv[t];
  xsv[t + 256] = xv[t + 256];
  __syncthreads();

  const int c  = t & 127;
  const int rg = (t >> 7) * 4;

  float acc[4] = {0.f, 0.f, 0.f, 0.f};
  float wa[4], wb[4];
  #pragma unroll
  for (int j = 0; j < 4; ++j) wa[j] = W[j * FOUT + c];
  #pragma unroll
  for (int j = 0; j < 4; ++j) wb[j] = W[(4 + j) * FOUT + c];

  for (int k4 = 0; k4 < FIN / 4; ++k4) {
    float wc[4];
    #pragma unroll
    for (int j = 0; j < 4; ++j) { wc[j] = wa[j]; wa[j] = wb[j]; }
    const int kn = (k4 + 2 < FIN / 4) ? k4 + 2 : k4;
    #pragma unroll
    for (int j = 0; j < 4; ++j) wb[j] = W[(kn * 4 + j) * FOUT + c];
    #pragma unroll
    for (int i = 0; i < 4; ++i) {
      const float4 xq = *(const float4*)&xs[(rg + i) * FIN + k4 * 4];
      acc[i] += xq.x * wc[0] + xq.y * wc[1] + xq.z * wc[2] + xq.w * wc[3];
    }
  }

  {
    const int j = R0 + rg;
    const int jb = j >> 5, q = (j >> 3) & 3, jj = j & 7;
    const int m = c & 15, nt = c >> 4;
    union { u16 u[4]; uint2 v; } pk;
    #pragma unroll
    for (int i = 0; i < 4; ++i) pk.u[i] = bf16_rne(acc[i]);
    *(uint2*)(hT3 + (size_t)(((jb * 8 + nt) * 64) + (m * 4 + q)) * 8 + jj) = pk.v;
  }

  const float a1 = a[c], a2 = a[FOUT + c];
  float s4[4], d4[4];
  #pragma unroll
  for (int i = 0; i < 4; ++i) { s4[i] = acc[i] * a1; d4[i] = acc[i] * a2; }
  #pragma unroll
  for (int off = 32; off > 0; off >>= 1) {
    #pragma unroll
    for (int i = 0; i < 4; ++i) {
      s4[i] += __shfl_down(s4[i], off);
      d4[i] += __shfl_down(d4[i], off);
    }
  }
  const int wv = t >> 6, lane = t & 63;
  if (lane == 0) {
    #pragma unroll
    for (int i = 0; i < 4; ++i) { partS[wv][i] = s4[i]; partD[wv][i] = d4[i]; }
  }
  __syncthreads();
  if (t < 16) {
    const int i = t & 3, rg2 = (t >> 2) & 1, which = t >> 3;
    if (which == 0) srcv[R0 + rg2 * 4 + i] = partS[rg2*2][i] + partS[rg2*2+1][i];
    else            dstv[R0 + rg2 * 4 + i] = partD[rg2*2][i] + partD[rg2*2+1][i];
  }
}

// ---------------------------------------------------------------------------
// Kernel 2: m97-style fused GAT, now with T4 counted-vmcnt barriers.
//
// OLD: B1/B2 were __syncthreads() -> B2's implicit vmcnt(0) drained the
// 16 KB DMA + adj prefetch with only the ~150-cy p-phase as cover; every
// tile paid a full memory round-trip ("<13% on every pipe").
// NEW: raw s_barrier; B2 waits lgkmcnt(0) ONLY (S ds_writes visible; DMA +
// reg loads stay in flight across it); B1 waits vmcnt(4) lgkmcnt(0) --
// retires exactly the 4 DMA chunks for the tile about to be consumed
// (oldest in the per-wave VMEM queue; sched_barrier fences pin 4xDMA
// before 4x reg-load issue order), never draining to 0 in the loop.
// Hazards: hS[buf^1] overwrite is safe (its last readers drained at B1's
// lgkmcnt(0)+barrier, DMA issues after); S overwrite safe the same way.
// ---------------------------------------------------------------------------
__global__ __launch_bounds__(256, 4) void k_gat(const int* __restrict__ adj,
                                                const u16* __restrict__ hT3,
                                                const float* __restrict__ srcv,
                                                const float* __restrict__ dstv,
                                                float* __restrict__ P,
                                                float* __restrict__ lp) {
  __shared__ u16 hS[2][8192];      // 2 x 16 KB staged hT tiles
  __shared__ u16 S[RB * SST];      // 4.6 KB p-tile (bf16)
  const int t = threadIdx.x;
  const int wv = t >> 6, lane = t & 63;
  const int q = lane >> 4, m = lane & 15;
  const int bm = blockIdx.x & 255;
  const int jp = blockIdx.x >> 8;
  const int R0 = bm * RB;
  const int j0 = jp * JSL;

  // p-phase mapping: thread -> (row pr, 8 cols at pc)
  const int pr = t >> 3;
  const int pc = (t & 7) * 8;
  const float srcr = srcv[R0 + pr];
  const int*   adjp = adj + (size_t)(R0 + pr) * N + j0 + pc;
  const float* dstp = dstv + j0 + pc;

  // MFMA mapping: wave -> (row-half rh, col-half ch)
  const int rh = wv & 1, ch = wv >> 1;
  const int Lq = m * 4 + q;                      // hT3/hS lane index

  floatx4 acc[4];
  #pragma unroll
  for (int nt = 0; nt < 4; ++nt) acc[nt] = (floatx4){0.f, 0.f, 0.f, 0.f};
  float lsum = 0.f;

  // DMA one tile (16 KB = 16 chunks of 1 KB); wave wv stages chunks wv*4..+4
  const size_t jb00 = (size_t)(j0 >> 5);         // first global jb of slice
  #define STAGE(I, BUF)                                                        \
  {                                                                            \
    _Pragma("unroll")                                                          \
    for (int cc = 0; cc < 4; ++cc) {                                           \
      const int kc = wv * 4 + cc;               /* 0..15 */                    \
      const int jbl = kc >> 3, nt_ = kc & 7;                                   \
      const u16* src = hT3 + ((jb00 + (size_t)(I) * 2 + jbl) * 8 + nt_) * 512  \
                       + (size_t)lane * 8;                                     \
      gl_lds16(src, &hS[BUF][kc * 512]);                                       \
    }                                                                          \
  }

  // prologue: stage tile 0 into buf 0; register-prefetch tile 0 adj/dst
  STAGE(0, 0)
  __builtin_amdgcn_sched_barrier(0);   // DMAs strictly oldest in VMEM queue
  int4   aC0 = *(const int4*)(adjp),     aC1 = *(const int4*)(adjp + 4);
  float4 dC0 = *(const float4*)(dstp),   dC1 = *(const float4*)(dstp + 4);

  int buf = 0;
  for (int i = 0; i < NTILE; ++i) {
    // B1: retire this tile's 4 DMA chunks (oldest); keep the 4 adj/dst
    // prefetch loads in flight. lgkmcnt(0): all waves' prior LDS reads done
    // before S / hS[buf^1] get overwritten after the barrier.
    asm volatile("s_waitcnt vmcnt(4) lgkmcnt(0)" ::: "memory");
    __builtin_amdgcn_s_barrier();
    __builtin_amdgcn_sched_barrier(0);

    // DMA tile i+1 into the other buffer; reg-prefetch adj/dst for tile i+1
    const int nx = (i + 1 < NTILE) ? i + 1 : i;
    if (i + 1 < NTILE) STAGE(i + 1, buf ^ 1)
    __builtin_amdgcn_sched_barrier(0);   // pin: 4 DMA issued before reg loads
    int4   aN0 = *(const int4*)(adjp + nx * TJ);
    int4   aN1 = *(const int4*)(adjp + nx * TJ + 4);
    float4 dN0 = *(const float4*)(dstp + nx * TJ);
    float4 dN1 = *(const float4*)(dstp + nx * TJ + 4);

    // p-phase: 8 p-values/thread from prefetched regs -> S (bf16)
    {
      const int   ai[8] = {aC0.x, aC0.y, aC0.z, aC0.w, aC1.x, aC1.y, aC1.z, aC1.w};
      const float df[8] = {dC0.x, dC0.y, dC0.z, dC0.w, dC1.x, dC1.y, dC1.z, dC1.w};
      union { u16 u[8]; short8 s; } pk;
      #pragma unroll
      for (int e = 0; e < 8; ++e) {
        float v = srcr + df[e];
        v = fmaxf(v, ALPHA * v);
        const float p = ai[e] > 0 ? __expf(v) : 0.f;
        lsum += p;
        pk.u[e] = bf16_rne(p);
      }
      *(short8*)&S[pr * SST + pc] = pk.s;
    }

    // B2: LDS-only barrier — S ds_writes visible to all waves; the DMA for
    // tile i+1 and the adj/dst loads remain in flight (no vmcnt drain).
    asm volatile("s_waitcnt lgkmcnt(0)" ::: "memory");
    __builtin_amdgcn_s_barrier();
    __builtin_amdgcn_sched_barrier(0);

    // MFMA: A-frags from S, B-frags from hS[buf]
    {
      const short8 a0 = *(const short8*)&S[(rh * 16 + m) * SST + q * 8];
      const short8 a1 = *(const short8*)&S[(rh * 16 + m) * SST + 32 + q * 8];
      #pragma unroll
      for (int nt = 0; nt < 4; ++nt) {
        const short8 b0 = *(const short8*)&hS[buf][(0 * 8 + ch * 4 + nt) * 512 + Lq * 8];
        const short8 b1 = *(const short8*)&hS[buf][(1 * 8 + ch * 4 + nt) * 512 + Lq * 8];
        acc[nt] = __builtin_amdgcn_mfma_f32_16x16x32_bf16(a0, b0, acc[nt], 0, 0, 0);
        acc[nt] = __builtin_amdgcn_mfma_f32_16x16x32_bf16(a1, b1, acc[nt], 0, 0, 0);
      }
    }

    aC0 = aN0; aC1 = aN1; dC0 = dN0; dC1 = dN1;
    buf ^= 1;
  }
  #undef STAGE

  // row-sum: reduce over the 8 threads sharing row pr (aligned groups)
  lsum += __shfl_down(lsum, 4);
  lsum += __shfl_down(lsum, 2);
  lsum += __shfl_down(lsum, 1);
  if ((t & 7) == 0) lp[(size_t)jp * N + R0 + pr] = lsum;

  // partial store (C/D layout: row = q*4+ri, col = nt*16+m)
  float* Pp = P + ((size_t)jp * N + R0 + rh * 16) * FOUT + ch * 64;
  #pragma unroll
  for (int nt = 0; nt < 4; ++nt)
    #pragma unroll
    for (int ri = 0; ri < 4; ++ri)
      Pp[(size_t)(q * 4 + ri) * FOUT + nt * 16 + m] = acc[nt][ri];
}

// ---------------------------------------------------------------------------
// Kernel 3: sum JP partials, normalize by row-sum. ~36 MB traffic.
// ---------------------------------------------------------------------------
__global__ __launch_bounds__(256) void k_norm(const float* __restrict__ P,
                                              const float* __restrict__ lp,
                                              float* __restrict__ out) {
  const int idx = blockIdx.x * 256 + threadIdx.x;   // 0 .. N*FOUT/4-1
  const int rr = idx >> 5;
  const int c4 = (idx & 31) * 4;
  float l = 0.f;
  #pragma unroll
  for (int j = 0; j < JP; ++j) l += lp[j * N + rr];
  const float inv = 1.0f / l;
  float4 s = {0.f, 0.f, 0.f, 0.f};
  #pragma unroll
  for (int j = 0; j < JP; ++j) {
    const float4 p = *(const float4*)(P + ((size_t)j * N + rr) * FOUT + c4);
    s.x += p.x; s.y += p.y; s.z += p.z; s.w += p.w;
  }
  s.x *= inv; s.y *= inv; s.z *= inv; s.w *= inv;
  *(float4*)(out + (size_t)rr * FOUT + c4) = s;
}

extern "C" void kernel_launch(void* const* d_in, const int* in_sizes, int n_in,
                              void* d_out, int out_size, void* d_ws, size_t ws_size,
                              hipStream_t stream) {
  const float* x   = (const float*)d_in[0];
  const int*   adj = (const int*)d_in[1];
  const float* W   = (const float*)d_in[2];
  const float* a   = (const float*)d_in[3];
  float* out = (float*)d_out;

  char* ws = (char*)d_ws;
  u16*   hT3  = (u16*)ws;     ws += (size_t)FOUT * N * sizeof(u16);            // 2 MB
  float* srcv = (float*)ws;   ws += (size_t)N * sizeof(float);
  float* dstv = (float*)ws;   ws += (size_t)N * sizeof(float);
  float* P    = (float*)ws;   ws += (size_t)JP * N * FOUT * sizeof(float);     // 16 MB
  float* lp   = (float*)ws;   ws += (size_t)JP * N * sizeof(float);

  k_proj<<<N / 8, 256, 0, stream>>>(x, W, a, hT3, srcv, dstv);
  k_gat <<<256 * JP, 256, 0, stream>>>(adj, hT3, srcv, dstv, P, lp);
  k_norm<<<(N * FOUT / 4) / 256, 256, 0, stream>>>(P, lp, out);
}

// Round 2
// 435.756 us; speedup vs baseline: 1.0036x; 1.0036x over previous
//
#include <hip/hip_runtime.h>
#include <cstdint>

#define N 8192
#define FIN 256
#define FOUT 128
#define ALPHA 0.2f
#define JP 4                  // j-split
#define JSL (N / JP)          // 2048 j per block
#define TJ 64                 // j-tile
#define NTILE (JSL / TJ)      // 32 tiles
#define RB 32                 // rows per block
#define SST 72                // S stride in u16 (16B-aligned rows, baseline banks)

typedef unsigned short u16;
typedef unsigned char u8;
typedef __attribute__((ext_vector_type(8))) short short8;
typedef __attribute__((ext_vector_type(4))) float floatx4;

__device__ __forceinline__ u16 bf16_rne(float f) {
  uint32_t u = __float_as_uint(f);
  u += 0x7fff + ((u >> 16) & 1);
  return (u16)(u >> 16);
}

// async global->LDS DMA, 16 B per lane, whole wave. LDS dest = uniform base
// + lane*16 (m104: wave-uniform base, lane-contiguous — layout must match).
__device__ __forceinline__ void gl_lds16(const void* g, void* l) {
  __builtin_amdgcn_global_load_lds(
      (const __attribute__((address_space(1))) void*)g,
      (__attribute__((address_space(3))) void*)l, 16, 0, 0);
}

// ---------------------------------------------------------------------------
// Kernel 0: adj (int32, 268 MB) -> bitmask (8 MB). Pure streaming, no
// barriers/phases — this is where the big adj read belongs (full HBM BW),
// instead of latency-capped inside k_gat's barrier-phased loop.
// Thread t packs 32 consecutive ints into one u32 (bit b = adj[t*32+b] > 0).
// Per-wave each unrolled dwordx4 load strides 128 B across lanes; the 8
// independent in-flight loads cover a contiguous 8 KB — streams fine.
// ---------------------------------------------------------------------------
__global__ __launch_bounds__(256) void k_pack(const int* __restrict__ adj,
                                              uint32_t* __restrict__ bm) {
  const int t = blockIdx.x * 256 + threadIdx.x;    // 0 .. N*N/32-1
  const int4* p = (const int4*)adj + (size_t)t * 8;
  int4 v[8];
  #pragma unroll
  for (int k = 0; k < 8; ++k) v[k] = p[k];
  uint32_t m = 0;
  #pragma unroll
  for (int k = 0; k < 8; ++k) {
    m |= (uint32_t)(v[k].x > 0) << (4 * k + 0);
    m |= (uint32_t)(v[k].y > 0) << (4 * k + 1);
    m |= (uint32_t)(v[k].z > 0) << (4 * k + 2);
    m |= (uint32_t)(v[k].w > 0) << (4 * k + 3);
  }
  bm[t] = m;
}

// ---------------------------------------------------------------------------
// Kernel 1: h = x@W (fp32); hT3 bf16 tiled [jb][nt][m*4+q][8] (1-KB chunks,
// DMA- and wave-contiguous); src = h@a1, dst = h@a2.  (unchanged)
// ---------------------------------------------------------------------------
__global__ __launch_bounds__(256) void k_proj(const float* __restrict__ x,
                                              const float* __restrict__ W,
                                              const float* __restrict__ a,
                                              u16* __restrict__ hT3,
                                              float* __restrict__ srcv,
                                              float* __restrict__ dstv) {
  __shared__ float xs[8 * FIN];                     // 8 KB
  __shared__ float partS[4][4], partD[4][4];
  const int t = threadIdx.x;
  const int R0 = blockIdx.x * 8;

  const float4* xv = (const float4*)(x + (size_t)R0 * FIN);
  float4* xsv = (float4*)xs;
  xsv[t] = xv[t];
  xsv[t + 256] = xv[t + 256];
  __syncthreads();

  const int c  = t & 127;
  const int rg = (t >> 7) * 4;

  float acc[4] = {0.f, 0.f, 0.f, 0.f};
  float wa[4], wb[4];
  #pragma unroll
  for (int j = 0; j < 4; ++j) wa[j] = W[j * FOUT + c];
  #pragma unroll
  for (int j = 0; j < 4; ++j) wb[j] = W[(4 + j) * FOUT + c];

  for (int k4 = 0; k4 < FIN / 4; ++k4) {
    float wc[4];
    #pragma unroll
    for (int j = 0; j < 4; ++j) { wc[j] = wa[j]; wa[j] = wb[j]; }
    const int kn = (k4 + 2 < FIN / 4) ? k4 + 2 : k4;
    #pragma unroll
    for (int j = 0; j < 4; ++j) wb[j] = W[(kn * 4 + j) * FOUT + c];
    #pragma unroll
    for (int i = 0; i < 4; ++i) {
      const float4 xq = *(const float4*)&xs[(rg + i) * FIN + k4 * 4];
      acc[i] += xq.x * wc[0] + xq.y * wc[1] + xq.z * wc[2] + xq.w * wc[3];
    }
  }

  {
    const int j = R0 + rg;
    const int jb = j >> 5, q = (j >> 3) & 3, jj = j & 7;
    const int m = c & 15, nt = c >> 4;
    union { u16 u[4]; uint2 v; } pk;
    #pragma unroll
    for (int i = 0; i < 4; ++i) pk.u[i] = bf16_rne(acc[i]);
    *(uint2*)(hT3 + (size_t)(((jb * 8 + nt) * 64) + (m * 4 + q)) * 8 + jj) = pk.v;
  }

  const float a1 = a[c], a2 = a[FOUT + c];
  float s4[4], d4[4];
  #pragma unroll
  for (int i = 0; i < 4; ++i) { s4[i] = acc[i] * a1; d4[i] = acc[i] * a2; }
  #pragma unroll
  for (int off = 32; off > 0; off >>= 1) {
    #pragma unroll
    for (int i = 0; i < 4; ++i) {
      s4[i] += __shfl_down(s4[i], off);
      d4[i] += __shfl_down(d4[i], off);
    }
  }
  const int wv = t >> 6, lane = t & 63;
  if (lane == 0) {
    #pragma unroll
    for (int i = 0; i < 4; ++i) { partS[wv][i] = s4[i]; partD[wv][i] = d4[i]; }
  }
  __syncthreads();
  if (t < 16) {
    const int i = t & 3, rg2 = (t >> 2) & 1, which = t >> 3;
    if (which == 0) srcv[R0 + rg2 * 4 + i] = partS[rg2*2][i] + partS[rg2*2+1][i];
    else            dstv[R0 + rg2 * 4 + i] = partD[rg2*2][i] + partD[rg2*2+1][i];
  }
}

// ---------------------------------------------------------------------------
// Kernel 2: m97-style fused GAT. Round-2 change: adj is consumed as a
// BITMASK (1 byte/thread/tile instead of 32 B) — k_gat's HBM demand drops
// 33x (268 MB -> 8 MB, L2/L3-resident), removing the latency-capped adj
// stream from the barrier-phased loop. Counted-vmcnt barriers kept from
// round 1: B1 = vmcnt(3) lgkmcnt(0) (per-iter in-flight = 4 DMA + 3 reg
// loads; 7-3=4 retires exactly the DMAs, which sched_barrier pins oldest);
// B2 = lgkmcnt(0) only (DMA + prefetch stay in flight across it).
// ---------------------------------------------------------------------------
__global__ __launch_bounds__(256, 4) void k_gat(const u8* __restrict__ bmk,
                                                const u16* __restrict__ hT3,
                                                const float* __restrict__ srcv,
                                                const float* __restrict__ dstv,
                                                float* __restrict__ P,
                                                float* __restrict__ lp) {
  __shared__ u16 hS[2][8192];      // 2 x 16 KB staged hT tiles
  __shared__ u16 S[RB * SST];      // 4.6 KB p-tile (bf16)
  const int t = threadIdx.x;
  const int wv = t >> 6, lane = t & 63;
  const int q = lane >> 4, m = lane & 15;
  const int bm = blockIdx.x & 255;
  const int jp = blockIdx.x >> 8;
  const int R0 = bm * RB;
  const int j0 = jp * JSL;

  // p-phase mapping: thread -> (row pr, 8 cols at pc)
  const int pr = t >> 3;
  const int pc = (t & 7) * 8;
  const float srcr = srcv[R0 + pr];
  // bitmask byte for (row R0+pr, cols j0+pc .. +7); per tile advance = 8 B
  const u8*    bmp  = bmk + (size_t)(R0 + pr) * (N / 8) + (j0 + pc) / 8;
  const float* dstp = dstv + j0 + pc;

  // MFMA mapping: wave -> (row-half rh, col-half ch)
  const int rh = wv & 1, ch = wv >> 1;
  const int Lq = m * 4 + q;                      // hT3/hS lane index

  floatx4 acc[4];
  #pragma unroll
  for (int nt = 0; nt < 4; ++nt) acc[nt] = (floatx4){0.f, 0.f, 0.f, 0.f};
  float lsum = 0.f;

  // DMA one tile (16 KB = 16 chunks of 1 KB); wave wv stages chunks wv*4..+4
  const size_t jb00 = (size_t)(j0 >> 5);         // first global jb of slice
  #define STAGE(I, BUF)                                                        \
  {                                                                            \
    _Pragma("unroll")                                                          \
    for (int cc = 0; cc < 4; ++cc) {                                           \
      const int kc = wv * 4 + cc;               /* 0..15 */                    \
      const int jbl = kc >> 3, nt_ = kc & 7;                                   \
      const u16* src = hT3 + ((jb00 + (size_t)(I) * 2 + jbl) * 8 + nt_) * 512  \
                       + (size_t)lane * 8;                                     \
      gl_lds16(src, &hS[BUF][kc * 512]);                                       \
    }                                                                          \
  }

  // prologue: stage tile 0 into buf 0; register-prefetch tile 0 mask/dst
  STAGE(0, 0)
  __builtin_amdgcn_sched_barrier(0);   // DMAs strictly oldest in VMEM queue
  u8     aC  = bmp[0];
  float4 dC0 = *(const float4*)(dstp),   dC1 = *(const float4*)(dstp + 4);

  int buf = 0;
  for (int i = 0; i < NTILE; ++i) {
    // B1: retire this tile's 4 DMA chunks (oldest); keep the 3 mask/dst
    // prefetch loads in flight. lgkmcnt(0): all waves' prior LDS reads done
    // before S / hS[buf^1] get overwritten after the barrier.
    asm volatile("s_waitcnt vmcnt(3) lgkmcnt(0)" ::: "memory");
    __builtin_amdgcn_s_barrier();
    __builtin_amdgcn_sched_barrier(0);

    // DMA tile i+1 into the other buffer; reg-prefetch mask/dst for tile i+1
    const int nx = (i + 1 < NTILE) ? i + 1 : i;
    if (i + 1 < NTILE) STAGE(i + 1, buf ^ 1)
    __builtin_amdgcn_sched_barrier(0);   // pin: 4 DMA issued before reg loads
    u8     aN  = bmp[nx * 8];
    float4 dN0 = *(const float4*)(dstp + nx * TJ);
    float4 dN1 = *(const float4*)(dstp + nx * TJ + 4);

    // p-phase: 8 p-values/thread from prefetched regs -> S (bf16)
    {
      const float df[8] = {dC0.x, dC0.y, dC0.z, dC0.w, dC1.x, dC1.y, dC1.z, dC1.w};
      union { u16 u[8]; short8 s; } pk;
      #pragma unroll
      for (int e = 0; e < 8; ++e) {
        float v = srcr + df[e];
        v = fmaxf(v, ALPHA * v);
        const float p = ((aC >> e) & 1) ? __expf(v) : 0.f;
        lsum += p;
        pk.u[e] = bf16_rne(p);
      }
      *(short8*)&S[pr * SST + pc] = pk.s;
    }

    // B2: LDS-only barrier — S ds_writes visible to all waves; the DMA for
    // tile i+1 and the mask/dst loads remain in flight (no vmcnt drain).
    asm volatile("s_waitcnt lgkmcnt(0)" ::: "memory");
    __builtin_amdgcn_s_barrier();
    __builtin_amdgcn_sched_barrier(0);

    // MFMA: A-frags from S, B-frags from hS[buf]
    {
      const short8 a0 = *(const short8*)&S[(rh * 16 + m) * SST + q * 8];
      const short8 a1 = *(const short8*)&S[(rh * 16 + m) * SST + 32 + q * 8];
      #pragma unroll
      for (int nt = 0; nt < 4; ++nt) {
        const short8 b0 = *(const short8*)&hS[buf][(0 * 8 + ch * 4 + nt) * 512 + Lq * 8];
        const short8 b1 = *(const short8*)&hS[buf][(1 * 8 + ch * 4 + nt) * 512 + Lq * 8];
        acc[nt] = __builtin_amdgcn_mfma_f32_16x16x32_bf16(a0, b0, acc[nt], 0, 0, 0);
        acc[nt] = __builtin_amdgcn_mfma_f32_16x16x32_bf16(a1, b1, acc[nt], 0, 0, 0);
      }
    }

    aC = aN; dC0 = dN0; dC1 = dN1;
    buf ^= 1;
  }
  #undef STAGE

  // row-sum: reduce over the 8 threads sharing row pr (aligned groups)
  lsum += __shfl_down(lsum, 4);
  lsum += __shfl_down(lsum, 2);
  lsum += __shfl_down(lsum, 1);
  if ((t & 7) == 0) lp[(size_t)jp * N + R0 + pr] = lsum;

  // partial store (C/D layout: row = q*4+ri, col = nt*16+m)
  float* Pp = P + ((size_t)jp * N + R0 + rh * 16) * FOUT + ch * 64;
  #pragma unroll
  for (int nt = 0; nt < 4; ++nt)
    #pragma unroll
    for (int ri = 0; ri < 4; ++ri)
      Pp[(size_t)(q * 4 + ri) * FOUT + nt * 16 + m] = acc[nt][ri];
}

// ---------------------------------------------------------------------------
// Kernel 3: sum JP partials, normalize by row-sum. ~36 MB traffic.
// ---------------------------------------------------------------------------
__global__ __launch_bounds__(256) void k_norm(const float* __restrict__ P,
                                              const float* __restrict__ lp,
                                              float* __restrict__ out) {
  const int idx = blockIdx.x * 256 + threadIdx.x;   // 0 .. N*FOUT/4-1
  const int rr = idx >> 5;
  const int c4 = (idx & 31) * 4;
  float l = 0.f;
  #pragma unroll
  for (int j = 0; j < JP; ++j) l += lp[j * N + rr];
  const float inv = 1.0f / l;
  float4 s = {0.f, 0.f, 0.f, 0.f};
  #pragma unroll
  for (int j = 0; j < JP; ++j) {
    const float4 p = *(const float4*)(P + ((size_t)j * N + rr) * FOUT + c4);
    s.x += p.x; s.y += p.y; s.z += p.z; s.w += p.w;
  }
  s.x *= inv; s.y *= inv; s.z *= inv; s.w *= inv;
  *(float4*)(out + (size_t)rr * FOUT + c4) = s;
}

extern "C" void kernel_launch(void* const* d_in, const int* in_sizes, int n_in,
                              void* d_out, int out_size, void* d_ws, size_t ws_size,
                              hipStream_t stream) {
  const float* x   = (const float*)d_in[0];
  const int*   adj = (const int*)d_in[1];
  const float* W   = (const float*)d_in[2];
  const float* a   = (const float*)d_in[3];
  float* out = (float*)d_out;

  char* ws = (char*)d_ws;
  u16*   hT3  = (u16*)ws;     ws += (size_t)FOUT * N * sizeof(u16);            // 2 MB
  float* srcv = (float*)ws;   ws += (size_t)N * sizeof(float);
  float* dstv = (float*)ws;   ws += (size_t)N * sizeof(float);
  float* P    = (float*)ws;   ws += (size_t)JP * N * FOUT * sizeof(float);     // 16 MB
  float* lp   = (float*)ws;   ws += (size_t)JP * N * sizeof(float);
  u8*    bmk  = (u8*)ws;      ws += (size_t)N * (N / 8);                       // 8 MB

  k_pack<<<(N / 32) * (N / 256), 256, 0, stream>>>(adj, (uint32_t*)bmk);
  k_proj<<<N / 8, 256, 0, stream>>>(x, W, a, hT3, srcv, dstv);
  k_gat <<<256 * JP, 256, 0, stream>>>(bmk, hT3, srcv, dstv, P, lp);
  k_norm<<<(N * FOUT / 4) / 256, 256, 0, stream>>>(P, lp, out);
}